// Round 6
// baseline (264.257 us; speedup 1.0000x reference)
//
#include <hip/hip_runtime.h>
#include <hip/hip_bf16.h>

// ThresholdEncode: x (N floats in [0,1)) -> (N, 64) float32 spike matrix.
// Row j (j < N-1): col 2i   = (x[j] <= th[i]) & (x[j+1] >  th[i])  (up)
//                  col 2i+1 = (x[j] >  th[i]) & (x[j+1] <= th[i])  (down)
// th[i] = float32( (i+1) * (1/33) computed in double )  -- matches np.linspace
// Row N-1: all zeros.
//
// Round-5 model: kernel ~87us = 2.9 TB/s on 256MB writes while the harness's
// own fill sustains 6.5 TB/s. Not VMEM-issue (250K wave-stores total), not
// VALU (~5us). Testing DRAM stream-count theory: fill-mimic shape —
// low occupancy (1024 blocks = 4 waves/SIMD), each WAVE owns a contiguous
// 62.5KB chunk, marching 1KB fully-contiguous wave-stores per iter.
// Thresholds are lane-invariant (c = lane&15) -> hoisted out of the loop.
// NOTE: nontemporal stores LOST WRITES under graph replay (round 3) — plain
// stores only.

typedef float f32x4 __attribute__((ext_vector_type(4)));

__global__ __launch_bounds__(256) void ThresholdEncode_kernel(
    const float* __restrict__ x, f32x4* __restrict__ out, int n) {
    const int total  = n * 16;                 // 16,000,000 float4s
    const int nwaves = gridDim.x * 4;          // 4 waves per 256-thread block
    // per-wave contiguous chunk, multiple of 64 so c = lane&15 is exact
    const int chunk  = (((total + nwaves - 1) / nwaves) + 63) & ~63;
    const int wid    = blockIdx.x * 4 + (threadIdx.x >> 6);
    const int lane   = threadIdx.x & 63;
    const int c      = lane & 15;              // quad within row — wave-invariant

    // Exact np.linspace(0,1,34,f32)[1:-1]: compute in double, round once.
    const float t0 = (float)((double)(2 * c + 1) * (1.0 / 33.0));
    const float t1 = (float)((double)(2 * c + 2) * (1.0 / 33.0));

    const int beg = wid * chunk;
    const int end = (beg + chunk < total) ? beg + chunk : total;

    #pragma unroll 4
    for (int f = beg + lane; f < end; f += 64) {   // wave writes 1KB/iter, sequential
        const int j = f >> 4;                      // row
        f32x4 v = (f32x4)(0.f, 0.f, 0.f, 0.f);
        if (j < n - 1) {
            const float xp = x[j];
            const float xn = x[j + 1];
            v.x = (xp <= t0 && xn >  t0) ? 1.0f : 0.0f;  // up   2c
            v.y = (xp >  t0 && xn <= t0) ? 1.0f : 0.0f;  // down 2c
            v.z = (xp <= t1 && xn >  t1) ? 1.0f : 0.0f;  // up   2c+1
            v.w = (xp >  t1 && xn <= t1) ? 1.0f : 0.0f;  // down 2c+1
        }
        out[f] = v;
    }
}

extern "C" void kernel_launch(void* const* d_in, const int* in_sizes, int n_in,
                              void* d_out, int out_size, void* d_ws, size_t ws_size,
                              hipStream_t stream) {
    const float* x = (const float*)d_in[0];
    f32x4* out = (f32x4*)d_out;
    const int n = in_sizes[0];                 // 1,000,000
    const int block = 256;
    const int grid = 1024;                     // 4 blocks/CU, 16 waves/CU (fill-like)
    ThresholdEncode_kernel<<<grid, block, 0, stream>>>(x, out, n);
}

// Round 7
// 245.850 us; speedup vs baseline: 1.0749x; 1.0749x over previous
//
#include <hip/hip_runtime.h>
#include <hip/hip_bf16.h>

// ThresholdEncode: x (N floats in [0,1)) -> (N, 64) float32 spike matrix.
// Row j (j < N-1): col 2i   = (x[j] <= th[i]) & (x[j+1] >  th[i])  (up)
//                  col 2i+1 = (x[j] >  th[i]) & (x[j+1] <= th[i])  (down)
// th[i] = float32((i+1) * (1/33) in double)  -- matches np.linspace. Last row 0.
//
// === DIAGNOSTIC ROUND ===
// R5 structure (best, ~87us-or-48us kernel — ambiguous), but the output is
// stored TWICE (identical values; compiler barrier prevents DCE of pass 1).
// Purpose: push our dispatch above the 155us poison fills so rocprof top-5
// shows OUR FETCH_SIZE / WRITE_SIZE / Occupancy / VALUBusy.
//   dur ~174us => single-pass writes ~3 TB/s (headroom remains)
//   dur ~100us => single-pass was ~48us, near write-floor
//   FETCH ~500MB => store RFO;  FETCH small => no RFO
// NOTE: nontemporal stores LOST WRITES under graph replay (round 3) — plain
// stores only.

typedef float f32x4 __attribute__((ext_vector_type(4)));

__global__ __launch_bounds__(256) void ThresholdEncode_kernel(
    const float* __restrict__ x, f32x4* __restrict__ out, int n) {
    const int t = blockIdx.x * 256 + threadIdx.x;
    const int ngroups = (n + 7) >> 3;          // groups of 8 rows
    if (t >= ngroups * 16) return;
    const int c  = t & 15;                     // quad (4 cols) within row
    const int g  = t >> 4;                     // row group
    const int j0 = g << 3;                     // first row of group

    // Exact np.linspace(0,1,34,f32)[1:-1]: compute in double, round once.
    const float t0 = (float)((double)(2 * c + 1) * (1.0 / 33.0));
    const float t1 = (float)((double)(2 * c + 2) * (1.0 / 33.0));

    // Load x[j0 .. j0+8] : two aligned float4 + one boundary scalar.
    float xv[9];
    if (j0 + 8 <= n) {
        const f32x4 a = *(const f32x4*)(x + j0);
        const f32x4 b = *(const f32x4*)(x + j0 + 4);
        xv[0]=a.x; xv[1]=a.y; xv[2]=a.z; xv[3]=a.w;
        xv[4]=b.x; xv[5]=b.y; xv[6]=b.z; xv[7]=b.w;
        xv[8] = (j0 + 8 < n) ? x[j0 + 8] : 0.0f;
    } else {
        #pragma unroll
        for (int k = 0; k < 9; ++k) xv[k] = (j0 + k < n) ? x[j0 + k] : 0.0f;
    }

    // Compute all 8 output quads into registers (static indexing).
    f32x4 vv[8];
    #pragma unroll
    for (int k = 0; k < 8; ++k) {
        f32x4 v = (f32x4)(0.f, 0.f, 0.f, 0.f);
        if (j0 + k < n - 1) {
            const float xp = xv[k];
            const float xn = xv[k + 1];
            v.x = (xp <= t0 && xn >  t0) ? 1.0f : 0.0f;
            v.y = (xp >  t0 && xn <= t0) ? 1.0f : 0.0f;
            v.z = (xp <= t1 && xn >  t1) ? 1.0f : 0.0f;
            v.w = (xp >  t1 && xn <= t1) ? 1.0f : 0.0f;
        }
        vv[k] = v;
    }

    // Pass 1.
    #pragma unroll
    for (int k = 0; k < 8; ++k)
        if (j0 + k < n) out[(j0 + k) * 16 + c] = vv[k];

    asm volatile("" ::: "memory");   // keep pass-1 stores (no DCE), order passes

    // Pass 2 — same addresses, same values: final memory state identical.
    #pragma unroll
    for (int k = 0; k < 8; ++k)
        if (j0 + k < n) out[(j0 + k) * 16 + c] = vv[k];
}

extern "C" void kernel_launch(void* const* d_in, const int* in_sizes, int n_in,
                              void* d_out, int out_size, void* d_ws, size_t ws_size,
                              hipStream_t stream) {
    const float* x = (const float*)d_in[0];
    f32x4* out = (f32x4*)d_out;
    const int n = in_sizes[0];                 // 1,000,000
    const int ngroups = (n + 7) >> 3;          // 125,000
    const int threads = ngroups * 16;          // 2,000,000
    const int block = 256;
    const int grid = (threads + block - 1) / block;  // 7,813 blocks
    ThresholdEncode_kernel<<<grid, block, 0, stream>>>(x, out, n);
}